// Round 4
// baseline (168.004 us; speedup 1.0000x reference)
//
#include <hip/hip_runtime.h>
#include <hip/hip_bf16.h>

#define S_LEN 4096
#define NEG_INF_F (-1e30f)

typedef __attribute__((ext_vector_type(4))) float f32x4;
typedef __attribute__((ext_vector_type(8))) short s16x8;
typedef unsigned short u16;

static __device__ __forceinline__ u16 f2bf(float f) {
    unsigned u = __builtin_bit_cast(unsigned, f);
    unsigned r = u + 0x7FFFu + ((u >> 16) & 1u);
    return (u16)(r >> 16);
}
static __device__ __forceinline__ float bf2f(u16 h) {
    unsigned u = ((unsigned)h) << 16;
    return __builtin_bit_cast(float, u);
}
static __device__ __forceinline__ void split4(const float4 v, ushort4& hi, ushort4& lo) {
    hi.x = f2bf(v.x); lo.x = f2bf(v.x - bf2f(hi.x));
    hi.y = f2bf(v.y); lo.y = f2bf(v.y - bf2f(hi.y));
    hi.z = f2bf(v.z); lo.z = f2bf(v.z - bf2f(hi.z));
    hi.w = f2bf(v.w); lo.w = f2bf(v.w - bf2f(hi.w));
}
static __device__ __forceinline__ void gl_lds16(const void* g, void* l) {
    __builtin_amdgcn_global_load_lds(
        (const __attribute__((address_space(1))) void*)g,
        (__attribute__((address_space(3))) void*)l, 16, 0, 0);
}
// swizzled u16 offset within a [rows][64 u16] LDS tile
static __device__ __forceinline__ int swz64(int row, int col_u16) {
    return row * 64 + (col_u16 ^ ((row & 7) << 3));
}
// swizzled u16 offset within a [rows][32 u16] LDS tile
static __device__ __forceinline__ int swz32(int row, int col_u16) {
    return row * 32 + (col_u16 ^ (((row >> 1) & 3) << 3));
}

// ---------------- K0: split x -> xh, xl (bf16 hi/lo) ----------------
__global__ __launch_bounds__(256) void split_kernel(
    const float* __restrict__ x, u16* __restrict__ xh, u16* __restrict__ xl) {
    size_t base = (size_t)blockIdx.x * 256 + threadIdx.x;
    #pragma unroll
    for (int i = 0; i < 4; ++i) {
        size_t idx = base + (size_t)i * 524288;
        float4 v = ((const float4*)x)[idx];
        ushort4 hi, lo; split4(v, hi, lo);
        ((ushort4*)xh)[idx] = hi;
        ((ushort4*)xl)[idx] = lo;
    }
}

// ---------------- K1: xT[b][d][s] = xh[b][s][d] ----------------
__global__ __launch_bounds__(256) void xt_kernel(
    const u16* __restrict__ xh, u16* __restrict__ xT) {
    const int bid = blockIdx.x;
    const int dt = bid & 7, st = (bid >> 3) & 63, b = bid >> 9;
    const int s0 = st * 64, d0 = dt * 64;
    __shared__ u16 T[64][72];
    const int tid = threadIdx.x;
    #pragma unroll
    for (int i = 0; i < 2; ++i) {
        int idx = i * 256 + tid;
        int r = idx >> 3, c8 = idx & 7;
        s16x8 v = *(const s16x8*)&xh[(size_t)(b * S_LEN + s0 + r) * 512 + d0 + c8 * 8];
        *(s16x8*)&T[r][c8 * 8] = v;
    }
    __syncthreads();
    #pragma unroll
    for (int i = 0; i < 2; ++i) {
        int idx = i * 256 + tid;
        int dr = idx >> 3, sc = idx & 7;
        s16x8 v;
        #pragma unroll
        for (int t = 0; t < 8; ++t) v[t] = (short)T[sc * 8 + t][dr];
        *(s16x8*)&xT[(size_t)(b * 512 + d0 + dr) * S_LEN + s0 + sc * 8] = v;
    }
}

// ---------------- K2: Mt = Wk^T @ Wq ----------------
__global__ __launch_bounds__(256) void mt_kernel(
    const float* __restrict__ Wk, const float* __restrict__ Wq,
    u16* __restrict__ Mth, u16* __restrict__ Mtl) {
    const int bm = blockIdx.x & 7, bn = blockIdx.x >> 3;
    const int m0 = bm * 64, n0 = bn * 64;
    __shared__ __align__(16) u16 Ath[64 * 72], Atl[64 * 72];
    __shared__ __align__(16) u16 Bth[64 * 72], Btl[64 * 72];
    const int tid = threadIdx.x, lane = tid & 63, w = tid >> 6;
    const int frow = lane & 15, fk = (lane >> 4) * 8;
    f32x4 acc[4] = {};

    for (int h0 = 0; h0 < 512; h0 += 64) {
        #pragma unroll
        for (int i = 0; i < 4; ++i) {
            int idx = i * 256 + tid;
            int h = idx >> 4, c4 = (idx & 15) * 4;
            float4 a = *(const float4*)(Wk + (size_t)(h0 + h) * 512 + m0 + c4);
            ushort4 ahi, alo; split4(a, ahi, alo);
            Ath[(c4 + 0) * 72 + h] = ahi.x; Atl[(c4 + 0) * 72 + h] = alo.x;
            Ath[(c4 + 1) * 72 + h] = ahi.y; Atl[(c4 + 1) * 72 + h] = alo.y;
            Ath[(c4 + 2) * 72 + h] = ahi.z; Atl[(c4 + 2) * 72 + h] = alo.z;
            Ath[(c4 + 3) * 72 + h] = ahi.w; Atl[(c4 + 3) * 72 + h] = alo.w;
            float4 b = *(const float4*)(Wq + (size_t)(h0 + h) * 512 + n0 + c4);
            ushort4 bhi, blo; split4(b, bhi, blo);
            Bth[(c4 + 0) * 72 + h] = bhi.x; Btl[(c4 + 0) * 72 + h] = blo.x;
            Bth[(c4 + 1) * 72 + h] = bhi.y; Btl[(c4 + 1) * 72 + h] = blo.y;
            Bth[(c4 + 2) * 72 + h] = bhi.z; Btl[(c4 + 2) * 72 + h] = blo.z;
            Bth[(c4 + 3) * 72 + h] = bhi.w; Btl[(c4 + 3) * 72 + h] = blo.w;
        }
        __syncthreads();
        #pragma unroll
        for (int kk = 0; kk < 2; ++kk) {
            s16x8 aH = *(const s16x8*)&Ath[(w * 16 + frow) * 72 + kk * 32 + fk];
            s16x8 aL = *(const s16x8*)&Atl[(w * 16 + frow) * 72 + kk * 32 + fk];
            #pragma unroll
            for (int ni = 0; ni < 4; ++ni) {
                s16x8 bH = *(const s16x8*)&Bth[(ni * 16 + frow) * 72 + kk * 32 + fk];
                s16x8 bL = *(const s16x8*)&Btl[(ni * 16 + frow) * 72 + kk * 32 + fk];
                acc[ni] = __builtin_amdgcn_mfma_f32_16x16x32_bf16(aH, bH, acc[ni], 0, 0, 0);
                acc[ni] = __builtin_amdgcn_mfma_f32_16x16x32_bf16(aH, bL, acc[ni], 0, 0, 0);
                acc[ni] = __builtin_amdgcn_mfma_f32_16x16x32_bf16(aL, bH, acc[ni], 0, 0, 0);
            }
        }
        __syncthreads();
    }
    #pragma unroll
    for (int ni = 0; ni < 4; ++ni) {
        int d1 = n0 + ni * 16 + frow;
        #pragma unroll
        for (int e = 0; e < 4; ++e) {
            int d2 = m0 + w * 16 + (lane >> 4) * 4 + e;
            float v = acc[ni][e];
            u16 hi = f2bf(v);
            Mth[(size_t)d2 * 512 + d1] = hi;
            Mtl[(size_t)d2 * 512 + d1] = f2bf(v - bf2f(hi));
        }
    }
}

// ---------------- K3: u = Wk^T @ bq ----------------
__global__ __launch_bounds__(256) void u_kernel(
    const float* __restrict__ Wk, const float* __restrict__ bq,
    float* __restrict__ u) {
    __shared__ float red[4][64];
    const int tid = threadIdx.x, c = tid & 63, hg = tid >> 6;
    const int d2 = blockIdx.x * 64 + c;
    float acc = 0.f;
    for (int h = hg; h < 512; h += 4) acc += Wk[(size_t)h * 512 + d2] * bq[h];
    red[hg][c] = acc;
    __syncthreads();
    if (hg == 0) u[d2] = red[0][c] + red[1][c] + red[2][c] + red[3][c];
}

// ---------------- K4: z = x @ Mt^T + u (double-buffered) ----------------
// grid 512 = 128 m-tiles x 4 n-tiles. block 512 (8 waves: 2 rg x 4 cg).
__global__ __launch_bounds__(512) void z_kernel(
    const u16* __restrict__ xh, const u16* __restrict__ xl,
    const u16* __restrict__ Mth, const u16* __restrict__ Mtl,
    const float* __restrict__ u, u16* __restrict__ zh, u16* __restrict__ zl) {
    const int bm = blockIdx.x >> 2, bn = blockIdx.x & 3;
    const int m0 = bm * 128, n0 = bn * 128;
    __shared__ __align__(16) u16 Ah[2][128 * 64], Al[2][128 * 64];
    __shared__ __align__(16) u16 Bh[2][128 * 64], Bl[2][128 * 64];
    const int tid = threadIdx.x, lane = tid & 63, w = tid >> 6;
    const int rg = w >> 2, cg = w & 3;
    const int frow = lane & 15, fkb = (lane >> 4) * 8;
    f32x4 acc[4][2] = {};

    auto stage = [&](int step, int buf) {
        const int k0 = step * 64;
        #pragma unroll
        for (int i = 0; i < 8; ++i) {
            int f = i * 512 + tid;
            int local = f & 1023;
            int r = local >> 3, c = local & 7;
            int sc = (c ^ (r & 7)) * 8;
            if (f < 1024)
                gl_lds16(xh + (size_t)(m0 + r) * 512 + k0 + sc, &Ah[buf][local * 8]);
            else if (f < 2048)
                gl_lds16(xl + (size_t)(m0 + r) * 512 + k0 + sc, &Al[buf][local * 8]);
            else if (f < 3072)
                gl_lds16(Mth + (size_t)(n0 + r) * 512 + k0 + sc, &Bh[buf][local * 8]);
            else
                gl_lds16(Mtl + (size_t)(n0 + r) * 512 + k0 + sc, &Bl[buf][local * 8]);
        }
    };

    stage(0, 0);
    __syncthreads();
    for (int t = 0; t < 8; ++t) {
        const int cur = t & 1;
        if (t < 7) stage(t + 1, cur ^ 1);
        #pragma unroll
        for (int kk = 0; kk < 2; ++kk) {
            s16x8 aH[4], aL[4], bH[2], bL[2];
            #pragma unroll
            for (int mi = 0; mi < 4; ++mi) {
                int row = rg * 64 + mi * 16 + frow;
                aH[mi] = *(const s16x8*)&Ah[cur][swz64(row, kk * 32 + fkb)];
                aL[mi] = *(const s16x8*)&Al[cur][swz64(row, kk * 32 + fkb)];
            }
            #pragma unroll
            for (int ni = 0; ni < 2; ++ni) {
                int row = cg * 32 + ni * 16 + frow;
                bH[ni] = *(const s16x8*)&Bh[cur][swz64(row, kk * 32 + fkb)];
                bL[ni] = *(const s16x8*)&Bl[cur][swz64(row, kk * 32 + fkb)];
            }
            #pragma unroll
            for (int mi = 0; mi < 4; ++mi)
                #pragma unroll
                for (int ni = 0; ni < 2; ++ni) {
                    acc[mi][ni] = __builtin_amdgcn_mfma_f32_16x16x32_bf16(aH[mi], bH[ni], acc[mi][ni], 0, 0, 0);
                    acc[mi][ni] = __builtin_amdgcn_mfma_f32_16x16x32_bf16(aH[mi], bL[ni], acc[mi][ni], 0, 0, 0);
                    acc[mi][ni] = __builtin_amdgcn_mfma_f32_16x16x32_bf16(aL[mi], bH[ni], acc[mi][ni], 0, 0, 0);
                }
        }
        __syncthreads();
    }
    #pragma unroll
    for (int ni = 0; ni < 2; ++ni) {
        int col = n0 + cg * 32 + ni * 16 + frow;
        float uv = u[col];
        #pragma unroll
        for (int mi = 0; mi < 4; ++mi) {
            int rbase = m0 + rg * 64 + mi * 16 + (lane >> 4) * 4;
            #pragma unroll
            for (int e = 0; e < 4; ++e) {
                float v = acc[mi][ni][e] + uv;
                u16 hi = f2bf(v);
                zh[(size_t)(rbase + e) * 512 + col] = hi;
                zl[(size_t)(rbase + e) * 512 + col] = f2bf(v - bf2f(hi));
            }
        }
    }
}

// ---------------- K5: banded scores + softmax -> P bf16 (double-buffered) ----------------
// grid 256 = 4b x 64 row-tiles. block 512 (8 waves: 4 row-groups x 2 window-halves).
__global__ __launch_bounds__(512) void score_kernel(
    const u16* __restrict__ zh, const u16* __restrict__ zl,
    const u16* __restrict__ xh, const u16* __restrict__ xl,
    u16* __restrict__ P) {
    const int bid = blockIdx.x;
    const int b = bid >> 6, it = bid & 63;
    const int i0 = it * 64, j0 = i0 - 128;
    const int mrow0 = b * S_LEN + i0;
    __shared__ __align__(16) u16 Qh[2][64 * 32], Ql[2][64 * 32];
    __shared__ __align__(16) u16 Kh[2][320 * 32], Kl[2][320 * 32];
    __shared__ float smax[64][2], ssum[64][2];

    const int tid = threadIdx.x, lane = tid & 63, w = tid >> 6;
    const int g = w >> 1, half = w & 1;
    const int frow = lane & 15, fk = (lane >> 4) * 8;
    const int tstart = g + (half ? 9 : 0);
    const int nt = half ? 8 : 9;

    f32x4 acc[9] = {};

    auto stage = [&](int step, int buf) {
        const int k0 = step * 32;
        #pragma unroll
        for (int i = 0; i < 6; ++i) {
            int f = i * 512 + tid;
            if (f < 256) {
                int r = f >> 2, c = f & 3;
                int sc = (c ^ ((r >> 1) & 3)) * 8;
                gl_lds16(zh + (size_t)(mrow0 + r) * 512 + k0 + sc, &Qh[buf][f * 8]);
            } else if (f < 512) {
                int l2 = f - 256, r = l2 >> 2, c = l2 & 3;
                int sc = (c ^ ((r >> 1) & 3)) * 8;
                gl_lds16(zl + (size_t)(mrow0 + r) * 512 + k0 + sc, &Ql[buf][l2 * 8]);
            } else if (f < 1792) {
                int l2 = f - 512, r = l2 >> 2, c = l2 & 3;
                int sc = (c ^ ((r >> 1) & 3)) * 8;
                int j = min(max(j0 + r, 0), S_LEN - 1);
                gl_lds16(xh + (size_t)(b * S_LEN + j) * 512 + k0 + sc, &Kh[buf][l2 * 8]);
            } else {
                int l2 = f - 1792, r = l2 >> 2, c = l2 & 3;
                int sc = (c ^ ((r >> 1) & 3)) * 8;
                int j = min(max(j0 + r, 0), S_LEN - 1);
                gl_lds16(xl + (size_t)(b * S_LEN + j) * 512 + k0 + sc, &Kl[buf][l2 * 8]);
            }
        }
    };

    stage(0, 0);
    __syncthreads();
    for (int t = 0; t < 16; ++t) {
        const int cur = t & 1;
        if (t < 15) stage(t + 1, cur ^ 1);
        const int qrow = g * 16 + frow;
        s16x8 aH = *(const s16x8*)&Qh[cur][swz32(qrow, fk)];
        s16x8 aL = *(const s16x8*)&Ql[cur][swz32(qrow, fk)];
        #pragma unroll
        for (int tt = 0; tt < 9; ++tt) {
            if (tt < nt) {
                int krow = (tstart + tt) * 16 + frow;
                s16x8 bH = *(const s16x8*)&Kh[cur][swz32(krow, fk)];
                s16x8 bL = *(const s16x8*)&Kl[cur][swz32(krow, fk)];
                acc[tt] = __builtin_amdgcn_mfma_f32_16x16x32_bf16(aH, bH, acc[tt], 0, 0, 0);
                acc[tt] = __builtin_amdgcn_mfma_f32_16x16x32_bf16(aH, bL, acc[tt], 0, 0, 0);
                acc[tt] = __builtin_amdgcn_mfma_f32_16x16x32_bf16(aL, bH, acc[tt], 0, 0, 0);
            }
        }
        __syncthreads();
    }

    const int rq = (lane >> 4) * 4;
    float mxh[4];
    #pragma unroll
    for (int e = 0; e < 4; ++e) {
        int r = g * 16 + rq + e;
        float m = NEG_INF_F;
        #pragma unroll
        for (int tt = 0; tt < 9; ++tt) {
            if (tt < nt) {
                int jj = (tstart + tt) * 16 + frow;
                int dj = jj - r, j = j0 + jj;
                if (dj >= 1 && dj <= 255 && j >= 0 && j < S_LEN) m = fmaxf(m, acc[tt][e]);
            }
        }
        #pragma unroll
        for (int d = 1; d < 16; d <<= 1) m = fmaxf(m, __shfl_xor(m, d));
        mxh[e] = m;
    }
    if (frow == 0) {
        #pragma unroll
        for (int e = 0; e < 4; ++e) smax[g * 16 + rq + e][half] = mxh[e];
    }
    __syncthreads();
    float p[9][4];
    float sh[4];
    #pragma unroll
    for (int e = 0; e < 4; ++e) {
        int r = g * 16 + rq + e;
        float mx = fmaxf(smax[r][0], smax[r][1]);
        float s = 0.f;
        #pragma unroll
        for (int tt = 0; tt < 9; ++tt) {
            float pv = 0.f;
            if (tt < nt) {
                int jj = (tstart + tt) * 16 + frow;
                int dj = jj - r, j = j0 + jj;
                bool valid = (dj >= 1 && dj <= 255 && j >= 0 && j < S_LEN);
                pv = valid ? __expf(acc[tt][e] - mx) : 0.f;
            }
            p[tt][e] = pv;
            s += pv;
        }
        #pragma unroll
        for (int d = 1; d < 16; d <<= 1) s += __shfl_xor(s, d);
        sh[e] = s;
    }
    if (frow == 0) {
        #pragma unroll
        for (int e = 0; e < 4; ++e) ssum[g * 16 + rq + e][half] = sh[e];
    }
    __syncthreads();
    float invv[4];
    #pragma unroll
    for (int e = 0; e < 4; ++e) {
        int r = g * 16 + rq + e;
        invv[e] = 1.f / (ssum[r][0] + ssum[r][1]);
    }
    #pragma unroll
    for (int tt = 0; tt < 9; ++tt) {
        if (tt < nt) {
            int t = tstart + tt;
            #pragma unroll
            for (int e = 0; e < 4; ++e) {
                int r = g * 16 + rq + e;
                P[(size_t)(mrow0 + r) * 320 + t * 16 + frow] = f2bf(p[tt][e] * invv[e]);
            }
        }
    }
    if (half == 0) {
        for (int t = 0; t < g; ++t)
            #pragma unroll
            for (int e = 0; e < 4; ++e)
                P[(size_t)(mrow0 + g * 16 + rq + e) * 320 + t * 16 + frow] = 0;
    } else {
        for (int t = g + 17; t < 20; ++t)
            #pragma unroll
            for (int e = 0; e < 4; ++e)
                P[(size_t)(mrow0 + g * 16 + rq + e) * 320 + t * 16 + frow] = 0;
    }
}

// ---------------- K6: out = P @ x_window (uses xT, double-buffered) ----------------
// grid 256 = 4b x 64 row-tiles. block 512 (8 waves: 2 row-groups x 4 d-blocks).
__global__ __launch_bounds__(512) void pv_kernel(
    const u16* __restrict__ P, const u16* __restrict__ xT,
    float* __restrict__ out) {
    const int bid = blockIdx.x;
    const int b = bid >> 6, it = bid & 63;
    const int i0 = it * 64, j0 = i0 - 128;
    const int mrow0 = b * S_LEN + i0;
    __shared__ __align__(16) u16 Ph[2][64 * 64];     // 16 KB
    __shared__ __align__(16) u16 XT[2][512 * 64];    // 128 KB
    const int tid = threadIdx.x, lane = tid & 63, w = tid >> 6;
    const int rg = w >> 2, dblk = w & 3;
    const int frow = lane & 15, fkb = (lane >> 4) * 8;
    f32x4 acc[2][8] = {};

    auto stage = [&](int step, int buf) {
        const int k0 = step * 64;
        #pragma unroll
        for (int i = 0; i < 9; ++i) {
            int f = i * 512 + tid;
            if (f < 512) {
                int r = f >> 3, c = f & 7;
                gl_lds16(P + (size_t)(mrow0 + r) * 320 + k0 + (c ^ (r & 7)) * 8,
                         &Ph[buf][f * 8]);
            } else {
                int l2 = f - 512, d = l2 >> 3, c = l2 & 7;
                int jb = j0 + k0 + (c ^ (d & 7)) * 8;
                jb = min(max(jb, 0), S_LEN - 8);
                gl_lds16(xT + (size_t)(b * 512 + d) * S_LEN + jb, &XT[buf][l2 * 8]);
            }
        }
    };

    stage(0, 0);
    __syncthreads();
    for (int t = 0; t < 5; ++t) {
        const int cur = t & 1;
        if (t < 4) stage(t + 1, cur ^ 1);
        #pragma unroll
        for (int kk = 0; kk < 2; ++kk) {
            s16x8 a[2];
            #pragma unroll
            for (int mi = 0; mi < 2; ++mi) {
                int row = rg * 32 + mi * 16 + frow;
                a[mi] = *(const s16x8*)&Ph[cur][swz64(row, kk * 32 + fkb)];
            }
            #pragma unroll
            for (int ni = 0; ni < 8; ++ni) {
                int drow = dblk * 128 + ni * 16 + frow;
                s16x8 bf = *(const s16x8*)&XT[cur][swz64(drow, kk * 32 + fkb)];
                acc[0][ni] = __builtin_amdgcn_mfma_f32_16x16x32_bf16(a[0], bf, acc[0][ni], 0, 0, 0);
                acc[1][ni] = __builtin_amdgcn_mfma_f32_16x16x32_bf16(a[1], bf, acc[1][ni], 0, 0, 0);
            }
        }
        __syncthreads();
    }
    #pragma unroll
    for (int mi = 0; mi < 2; ++mi) {
        #pragma unroll
        for (int ni = 0; ni < 8; ++ni) {
            int cidx = dblk * 128 + ni * 16 + frow;
            #pragma unroll
            for (int e = 0; e < 4; ++e) {
                int r = mrow0 + rg * 32 + mi * 16 + (lane >> 4) * 4 + e;
                out[(size_t)r * 512 + cidx] = acc[mi][ni][e];
            }
        }
    }
}

extern "C" void kernel_launch(void* const* d_in, const int* in_sizes, int n_in,
                              void* d_out, int out_size, void* d_ws, size_t ws_size,
                              hipStream_t stream) {
    const float* x  = (const float*)d_in[0];
    const float* Wq = (const float*)d_in[1];
    const float* bq = (const float*)d_in[2];
    const float* Wk = (const float*)d_in[3];
    const float* bk = (const float*)d_in[4];
    (void)bk;
    float* out = (float*)d_out;

    u16* xh  = (u16*)d_ws;
    u16* xl  = xh + (size_t)8388608;
    u16* zh  = xl + (size_t)8388608;
    u16* zl  = zh + (size_t)8388608;
    u16* Mth = zl + (size_t)8388608;
    u16* Mtl = Mth + (size_t)262144;
    u16* Pb  = Mtl + (size_t)262144;
    float* uv = (float*)(Pb + (size_t)16384 * 320);
    u16* xT  = zh;   // alias: zh/zl dead after score_kernel, xT written after

    hipLaunchKernelGGL(split_kernel, dim3(2048), dim3(256), 0, stream, x, xh, xl);
    hipLaunchKernelGGL(mt_kernel, dim3(64), dim3(256), 0, stream, Wk, Wq, Mth, Mtl);
    hipLaunchKernelGGL(u_kernel, dim3(8), dim3(256), 0, stream, Wk, bq, uv);
    hipLaunchKernelGGL(z_kernel, dim3(512), dim3(512), 0, stream,
                       xh, xl, Mth, Mtl, uv, zh, zl);
    hipLaunchKernelGGL(score_kernel, dim3(256), dim3(512), 0, stream,
                       zh, zl, xh, xl, Pb);
    hipLaunchKernelGGL(xt_kernel, dim3(2048), dim3(256), 0, stream, xh, xT);
    hipLaunchKernelGGL(pv_kernel, dim3(256), dim3(512), 0, stream, Pb, xT, out);
}

// Round 5
// 166.455 us; speedup vs baseline: 1.0093x; 1.0093x over previous
//
#include <hip/hip_runtime.h>
#include <hip/hip_bf16.h>

#define S_LEN 4096
#define NEG_INF_F (-1e30f)

typedef __attribute__((ext_vector_type(4))) float f32x4;
typedef __attribute__((ext_vector_type(8))) short s16x8;
typedef unsigned short u16;

static __device__ __forceinline__ u16 f2bf(float f) {
    unsigned u = __builtin_bit_cast(unsigned, f);
    unsigned r = u + 0x7FFFu + ((u >> 16) & 1u);
    return (u16)(r >> 16);
}
static __device__ __forceinline__ float bf2f(u16 h) {
    unsigned u = ((unsigned)h) << 16;
    return __builtin_bit_cast(float, u);
}
static __device__ __forceinline__ void split4(const float4 v, ushort4& hi, ushort4& lo) {
    hi.x = f2bf(v.x); lo.x = f2bf(v.x - bf2f(hi.x));
    hi.y = f2bf(v.y); lo.y = f2bf(v.y - bf2f(hi.y));
    hi.z = f2bf(v.z); lo.z = f2bf(v.z - bf2f(hi.z));
    hi.w = f2bf(v.w); lo.w = f2bf(v.w - bf2f(hi.w));
}
static __device__ __forceinline__ void gl_lds16(const void* g, void* l) {
    __builtin_amdgcn_global_load_lds(
        (const __attribute__((address_space(1))) void*)g,
        (__attribute__((address_space(3))) void*)l, 16, 0, 0);
}
// swizzled u16 offset within a [rows][64 u16] LDS tile
static __device__ __forceinline__ int swz64(int row, int col_u16) {
    return row * 64 + (col_u16 ^ ((row & 7) << 3));
}

// ---------------- K0: split x -> xh, xl (bf16 hi/lo) ----------------
__global__ __launch_bounds__(256) void split_kernel(
    const float* __restrict__ x, u16* __restrict__ xh, u16* __restrict__ xl) {
    size_t base = (size_t)blockIdx.x * 256 + threadIdx.x;
    #pragma unroll
    for (int i = 0; i < 4; ++i) {
        size_t idx = base + (size_t)i * 524288;
        float4 v = ((const float4*)x)[idx];
        ushort4 hi, lo; split4(v, hi, lo);
        ((ushort4*)xh)[idx] = hi;
        ((ushort4*)xl)[idx] = lo;
    }
}

// ---------------- K1: xT[b][d][s] = xh[b][s][d] ----------------
__global__ __launch_bounds__(256) void xt_kernel(
    const u16* __restrict__ xh, u16* __restrict__ xT) {
    const int bid = blockIdx.x;
    const int dt = bid & 7, st = (bid >> 3) & 63, b = bid >> 9;
    const int s0 = st * 64, d0 = dt * 64;
    __shared__ u16 T[64][72];
    const int tid = threadIdx.x;
    #pragma unroll
    for (int i = 0; i < 2; ++i) {
        int idx = i * 256 + tid;
        int r = idx >> 3, c8 = idx & 7;
        s16x8 v = *(const s16x8*)&xh[(size_t)(b * S_LEN + s0 + r) * 512 + d0 + c8 * 8];
        *(s16x8*)&T[r][c8 * 8] = v;
    }
    __syncthreads();
    #pragma unroll
    for (int i = 0; i < 2; ++i) {
        int idx = i * 256 + tid;
        int dr = idx >> 3, sc = idx & 7;
        s16x8 v;
        #pragma unroll
        for (int t = 0; t < 8; ++t) v[t] = (short)T[sc * 8 + t][dr];
        *(s16x8*)&xT[(size_t)(b * 512 + d0 + dr) * S_LEN + s0 + sc * 8] = v;
    }
}

// ---------------- K2: Mt = Wk^T @ Wq ----------------
__global__ __launch_bounds__(256) void mt_kernel(
    const float* __restrict__ Wk, const float* __restrict__ Wq,
    u16* __restrict__ Mth, u16* __restrict__ Mtl) {
    const int bm = blockIdx.x & 7, bn = blockIdx.x >> 3;
    const int m0 = bm * 64, n0 = bn * 64;
    __shared__ __align__(16) u16 Ath[64 * 72], Atl[64 * 72];
    __shared__ __align__(16) u16 Bth[64 * 72], Btl[64 * 72];
    const int tid = threadIdx.x, lane = tid & 63, w = tid >> 6;
    const int frow = lane & 15, fk = (lane >> 4) * 8;
    f32x4 acc[4] = {};

    for (int h0 = 0; h0 < 512; h0 += 64) {
        #pragma unroll
        for (int i = 0; i < 4; ++i) {
            int idx = i * 256 + tid;
            int h = idx >> 4, c4 = (idx & 15) * 4;
            float4 a = *(const float4*)(Wk + (size_t)(h0 + h) * 512 + m0 + c4);
            ushort4 ahi, alo; split4(a, ahi, alo);
            Ath[(c4 + 0) * 72 + h] = ahi.x; Atl[(c4 + 0) * 72 + h] = alo.x;
            Ath[(c4 + 1) * 72 + h] = ahi.y; Atl[(c4 + 1) * 72 + h] = alo.y;
            Ath[(c4 + 2) * 72 + h] = ahi.z; Atl[(c4 + 2) * 72 + h] = alo.z;
            Ath[(c4 + 3) * 72 + h] = ahi.w; Atl[(c4 + 3) * 72 + h] = alo.w;
            float4 b = *(const float4*)(Wq + (size_t)(h0 + h) * 512 + n0 + c4);
            ushort4 bhi, blo; split4(b, bhi, blo);
            Bth[(c4 + 0) * 72 + h] = bhi.x; Btl[(c4 + 0) * 72 + h] = blo.x;
            Bth[(c4 + 1) * 72 + h] = bhi.y; Btl[(c4 + 1) * 72 + h] = blo.y;
            Bth[(c4 + 2) * 72 + h] = bhi.z; Btl[(c4 + 2) * 72 + h] = blo.z;
            Bth[(c4 + 3) * 72 + h] = bhi.w; Btl[(c4 + 3) * 72 + h] = blo.w;
        }
        __syncthreads();
        #pragma unroll
        for (int kk = 0; kk < 2; ++kk) {
            s16x8 aH = *(const s16x8*)&Ath[(w * 16 + frow) * 72 + kk * 32 + fk];
            s16x8 aL = *(const s16x8*)&Atl[(w * 16 + frow) * 72 + kk * 32 + fk];
            #pragma unroll
            for (int ni = 0; ni < 4; ++ni) {
                s16x8 bH = *(const s16x8*)&Bth[(ni * 16 + frow) * 72 + kk * 32 + fk];
                s16x8 bL = *(const s16x8*)&Btl[(ni * 16 + frow) * 72 + kk * 32 + fk];
                acc[ni] = __builtin_amdgcn_mfma_f32_16x16x32_bf16(aH, bH, acc[ni], 0, 0, 0);
                acc[ni] = __builtin_amdgcn_mfma_f32_16x16x32_bf16(aH, bL, acc[ni], 0, 0, 0);
                acc[ni] = __builtin_amdgcn_mfma_f32_16x16x32_bf16(aL, bH, acc[ni], 0, 0, 0);
            }
        }
        __syncthreads();
    }
    #pragma unroll
    for (int ni = 0; ni < 4; ++ni) {
        int d1 = n0 + ni * 16 + frow;
        #pragma unroll
        for (int e = 0; e < 4; ++e) {
            int d2 = m0 + w * 16 + (lane >> 4) * 4 + e;
            float v = acc[ni][e];
            u16 hi = f2bf(v);
            Mth[(size_t)d2 * 512 + d1] = hi;
            Mtl[(size_t)d2 * 512 + d1] = f2bf(v - bf2f(hi));
        }
    }
}

// ---------------- K3: u = Wk^T @ bq ----------------
__global__ __launch_bounds__(256) void u_kernel(
    const float* __restrict__ Wk, const float* __restrict__ bq,
    float* __restrict__ u) {
    __shared__ float red[4][64];
    const int tid = threadIdx.x, c = tid & 63, hg = tid >> 6;
    const int d2 = blockIdx.x * 64 + c;
    float acc = 0.f;
    for (int h = hg; h < 512; h += 4) acc += Wk[(size_t)h * 512 + d2] * bq[h];
    red[hg][c] = acc;
    __syncthreads();
    if (hg == 0) u[d2] = red[0][c] + red[1][c] + red[2][c] + red[3][c];
}

// ---------------- K4: z = x @ Mt^T + u (single-buffer, 2 blocks/CU) ----------------
// grid 512 = 128 m-tiles x 4 n-tiles. block 512 (8 waves: 2 rg x 4 cg).
__global__ __launch_bounds__(512) void z_kernel(
    const u16* __restrict__ xh, const u16* __restrict__ xl,
    const u16* __restrict__ Mth, const u16* __restrict__ Mtl,
    const float* __restrict__ u, u16* __restrict__ zh, u16* __restrict__ zl) {
    const int bm = blockIdx.x >> 2, bn = blockIdx.x & 3;
    const int m0 = bm * 128, n0 = bn * 128;
    __shared__ __align__(16) u16 Ah[128 * 64], Al[128 * 64];
    __shared__ __align__(16) u16 Bh[128 * 64], Bl[128 * 64];
    const int tid = threadIdx.x, lane = tid & 63, w = tid >> 6;
    const int rg = w >> 2, cg = w & 3;
    const int frow = lane & 15, fk = (lane >> 4) * 8;
    f32x4 acc[4][2] = {};

    for (int k0 = 0; k0 < 512; k0 += 64) {
        #pragma unroll
        for (int i = 0; i < 2; ++i) {
            int idx = i * 512 + tid;          // 1024 chunks per array
            int r = idx >> 3, c = idx & 7;
            int sc = (c ^ (r & 7)) * 8;
            gl_lds16(xh + (size_t)(m0 + r) * 512 + k0 + sc, &Ah[idx * 8]);
            gl_lds16(xl + (size_t)(m0 + r) * 512 + k0 + sc, &Al[idx * 8]);
            gl_lds16(Mth + (size_t)(n0 + r) * 512 + k0 + sc, &Bh[idx * 8]);
            gl_lds16(Mtl + (size_t)(n0 + r) * 512 + k0 + sc, &Bl[idx * 8]);
        }
        __syncthreads();
        #pragma unroll
        for (int kk = 0; kk < 2; ++kk) {
            s16x8 aH[4], aL[4], bH[2], bL[2];
            #pragma unroll
            for (int mi = 0; mi < 4; ++mi) {
                int row = rg * 64 + mi * 16 + frow;
                aH[mi] = *(const s16x8*)&Ah[swz64(row, kk * 32 + fk)];
                aL[mi] = *(const s16x8*)&Al[swz64(row, kk * 32 + fk)];
            }
            #pragma unroll
            for (int ni = 0; ni < 2; ++ni) {
                int row = cg * 32 + ni * 16 + frow;
                bH[ni] = *(const s16x8*)&Bh[swz64(row, kk * 32 + fk)];
                bL[ni] = *(const s16x8*)&Bl[swz64(row, kk * 32 + fk)];
            }
            #pragma unroll
            for (int mi = 0; mi < 4; ++mi)
                #pragma unroll
                for (int ni = 0; ni < 2; ++ni) {
                    acc[mi][ni] = __builtin_amdgcn_mfma_f32_16x16x32_bf16(aH[mi], bH[ni], acc[mi][ni], 0, 0, 0);
                    acc[mi][ni] = __builtin_amdgcn_mfma_f32_16x16x32_bf16(aH[mi], bL[ni], acc[mi][ni], 0, 0, 0);
                    acc[mi][ni] = __builtin_amdgcn_mfma_f32_16x16x32_bf16(aL[mi], bH[ni], acc[mi][ni], 0, 0, 0);
                }
        }
        __syncthreads();
    }
    #pragma unroll
    for (int ni = 0; ni < 2; ++ni) {
        int col = n0 + cg * 32 + ni * 16 + frow;
        float uv = u[col];
        #pragma unroll
        for (int mi = 0; mi < 4; ++mi) {
            int rbase = m0 + rg * 64 + mi * 16 + (lane >> 4) * 4;
            #pragma unroll
            for (int e = 0; e < 4; ++e) {
                float v = acc[mi][ni][e] + uv;
                u16 hi = f2bf(v);
                zh[(size_t)(rbase + e) * 512 + col] = hi;
                zl[(size_t)(rbase + e) * 512 + col] = f2bf(v - bf2f(hi));
            }
        }
    }
}

// ---------------- K5: banded scores + softmax -> P bf16 ----------------
// grid 256 = 4b x 64 row-tiles. block 512 (8 waves: 4 row-groups x 2 halves).
// LDS = K hi/lo only (exactly 80 KB) -> 2 blocks/CU. Q loaded global->reg.
// Softmax cross-wave stats aliased into Kh/Kl after the K loop.
__global__ __launch_bounds__(512, 4) void score_kernel(
    const u16* __restrict__ zh, const u16* __restrict__ zl,
    const u16* __restrict__ xh, const u16* __restrict__ xl,
    u16* __restrict__ P) {
    const int bid = blockIdx.x;
    const int b = bid >> 6, it = bid & 63;
    const int i0 = it * 64, j0 = i0 - 128;
    const int mrow0 = b * S_LEN + i0;
    __shared__ __align__(16) u16 Kh[320 * 64], Kl[320 * 64];   // 80 KB total

    const int tid = threadIdx.x, lane = tid & 63, w = tid >> 6;
    const int g = w >> 1, half = w & 1;
    const int frow = lane & 15, fk = (lane >> 4) * 8;
    const int tstart = g + (half ? 9 : 0);
    const int nt = half ? 8 : 9;
    const size_t qoff = (size_t)(mrow0 + g * 16 + frow) * 512;

    f32x4 acc[9] = {};

    for (int t = 0; t < 8; ++t) {
        const int k0 = t * 64;
        // Q fragments: global -> registers (z is L2/L3 resident)
        s16x8 aH0 = *(const s16x8*)(zh + qoff + k0 + fk);
        s16x8 aH1 = *(const s16x8*)(zh + qoff + k0 + 32 + fk);
        s16x8 aL0 = *(const s16x8*)(zl + qoff + k0 + fk);
        s16x8 aL1 = *(const s16x8*)(zl + qoff + k0 + 32 + fk);
        // K window: global -> LDS (2560 16B-chunks per array)
        #pragma unroll
        for (int i = 0; i < 5; ++i) {
            int idx = i * 512 + tid;
            int r = idx >> 3, c = idx & 7;
            int sc = (c ^ (r & 7)) * 8;
            int j = min(max(j0 + r, 0), S_LEN - 1);
            gl_lds16(xh + (size_t)(b * S_LEN + j) * 512 + k0 + sc, &Kh[idx * 8]);
        }
        #pragma unroll
        for (int i = 0; i < 5; ++i) {
            int idx = i * 512 + tid;
            int r = idx >> 3, c = idx & 7;
            int sc = (c ^ (r & 7)) * 8;
            int j = min(max(j0 + r, 0), S_LEN - 1);
            gl_lds16(xl + (size_t)(b * S_LEN + j) * 512 + k0 + sc, &Kl[idx * 8]);
        }
        __syncthreads();
        #pragma unroll
        for (int kk = 0; kk < 2; ++kk) {
            s16x8 aH = kk ? aH1 : aH0;
            s16x8 aL = kk ? aL1 : aL0;
            #pragma unroll
            for (int tt = 0; tt < 9; ++tt) {
                if (tt < nt) {
                    int krow = (tstart + tt) * 16 + frow;
                    s16x8 bH = *(const s16x8*)&Kh[swz64(krow, kk * 32 + fk)];
                    s16x8 bL = *(const s16x8*)&Kl[swz64(krow, kk * 32 + fk)];
                    acc[tt] = __builtin_amdgcn_mfma_f32_16x16x32_bf16(aH, bH, acc[tt], 0, 0, 0);
                    acc[tt] = __builtin_amdgcn_mfma_f32_16x16x32_bf16(aH, bL, acc[tt], 0, 0, 0);
                    acc[tt] = __builtin_amdgcn_mfma_f32_16x16x32_bf16(aL, bH, acc[tt], 0, 0, 0);
                }
            }
        }
        __syncthreads();
    }

    // ---- softmax; stats in LDS aliased onto dead K buffers ----
    float* sred_max = (float*)Kh;   // [64][2]
    float* sred_sum = (float*)Kl;   // [64][2]
    const int rq = (lane >> 4) * 4;

    #pragma unroll
    for (int e = 0; e < 4; ++e) {
        int r = g * 16 + rq + e;
        float m = NEG_INF_F;
        #pragma unroll
        for (int tt = 0; tt < 9; ++tt) {
            if (tt < nt) {
                int jj = (tstart + tt) * 16 + frow;
                int dj = jj - r, j = j0 + jj;
                if (dj >= 1 && dj <= 255 && j >= 0 && j < S_LEN) m = fmaxf(m, acc[tt][e]);
            }
        }
        #pragma unroll
        for (int d = 1; d < 16; d <<= 1) m = fmaxf(m, __shfl_xor(m, d));
        if (frow == 0) sred_max[r * 2 + half] = m;
    }
    __syncthreads();
    float sh[4];
    #pragma unroll
    for (int e = 0; e < 4; ++e) {
        int r = g * 16 + rq + e;
        float mx = fmaxf(sred_max[r * 2], sred_max[r * 2 + 1]);
        float s = 0.f;
        #pragma unroll
        for (int tt = 0; tt < 9; ++tt) {
            float pv = 0.f;
            if (tt < nt) {
                int jj = (tstart + tt) * 16 + frow;
                int dj = jj - r, j = j0 + jj;
                bool valid = (dj >= 1 && dj <= 255 && j >= 0 && j < S_LEN);
                pv = valid ? __expf(acc[tt][e] - mx) : 0.f;
            }
            acc[tt][e] = pv;                 // reuse acc as p
            s += pv;
        }
        #pragma unroll
        for (int d = 1; d < 16; d <<= 1) s += __shfl_xor(s, d);
        sh[e] = s;
    }
    if (frow == 0) {
        #pragma unroll
        for (int e = 0; e < 4; ++e) sred_sum[(g * 16 + rq + e) * 2 + half] = sh[e];
    }
    __syncthreads();
    float invv[4];
    #pragma unroll
    for (int e = 0; e < 4; ++e) {
        int r = g * 16 + rq + e;
        invv[e] = 1.f / (sred_sum[r * 2] + sred_sum[r * 2 + 1]);
    }
    #pragma unroll
    for (int tt = 0; tt < 9; ++tt) {
        if (tt < nt) {
            int t = tstart + tt;
            #pragma unroll
            for (int e = 0; e < 4; ++e) {
                int r = g * 16 + rq + e;
                P[(size_t)(mrow0 + r) * 320 + t * 16 + frow] = f2bf(acc[tt][e] * invv[e]);
            }
        }
    }
    if (half == 0) {
        for (int t = 0; t < g; ++t)
            #pragma unroll
            for (int e = 0; e < 4; ++e)
                P[(size_t)(mrow0 + g * 16 + rq + e) * 320 + t * 16 + frow] = 0;
    } else {
        for (int t = g + 17; t < 20; ++t)
            #pragma unroll
            for (int e = 0; e < 4; ++e)
                P[(size_t)(mrow0 + g * 16 + rq + e) * 320 + t * 16 + frow] = 0;
    }
}

// ---------------- K6: out = P @ x_window (uses xT, single-buffer) ----------------
// grid 256 = 4b x 64 row-tiles. block 512 (8 waves: 2 row-groups x 4 d-blocks).
__global__ __launch_bounds__(512) void pv_kernel(
    const u16* __restrict__ P, const u16* __restrict__ xT,
    float* __restrict__ out) {
    const int bid = blockIdx.x;
    const int b = bid >> 6, it = bid & 63;
    const int i0 = it * 64, j0 = i0 - 128;
    const int mrow0 = b * S_LEN + i0;
    __shared__ __align__(16) u16 Ph[64 * 64];    // 8 KB
    __shared__ __align__(16) u16 XT[512 * 64];   // 64 KB
    const int tid = threadIdx.x, lane = tid & 63, w = tid >> 6;
    const int rg = w >> 2, dblk = w & 3;
    const int frow = lane & 15, fkb = (lane >> 4) * 8;
    f32x4 acc[2][8] = {};

    for (int k0 = 0; k0 < 320; k0 += 64) {
        {
            int idx = tid;                       // 512 chunks (64 rows x 8)
            int r = idx >> 3, c = idx & 7;
            gl_lds16(P + (size_t)(mrow0 + r) * 320 + k0 + (c ^ (r & 7)) * 8, &Ph[idx * 8]);
        }
        #pragma unroll
        for (int i = 0; i < 8; ++i) {
            int idx = i * 512 + tid;             // 4096 chunks (512 d-rows x 8)
            int d = idx >> 3, c = idx & 7;
            int jb = j0 + k0 + (c ^ (d & 7)) * 8;
            jb = min(max(jb, 0), S_LEN - 8);     // clamped edges: P==0 there
            gl_lds16(xT + (size_t)(b * 512 + d) * S_LEN + jb, &XT[idx * 8]);
        }
        __syncthreads();
        #pragma unroll
        for (int kk = 0; kk < 2; ++kk) {
            s16x8 a[2];
            #pragma unroll
            for (int mi = 0; mi < 2; ++mi) {
                int row = rg * 32 + mi * 16 + frow;
                a[mi] = *(const s16x8*)&Ph[swz64(row, kk * 32 + fkb)];
            }
            #pragma unroll
            for (int ni = 0; ni < 8; ++ni) {
                int drow = dblk * 128 + ni * 16 + frow;
                s16x8 bf = *(const s16x8*)&XT[swz64(drow, kk * 32 + fkb)];
                acc[0][ni] = __builtin_amdgcn_mfma_f32_16x16x32_bf16(a[0], bf, acc[0][ni], 0, 0, 0);
                acc[1][ni] = __builtin_amdgcn_mfma_f32_16x16x32_bf16(a[1], bf, acc[1][ni], 0, 0, 0);
            }
        }
        __syncthreads();
    }
    #pragma unroll
    for (int mi = 0; mi < 2; ++mi) {
        #pragma unroll
        for (int ni = 0; ni < 8; ++ni) {
            int cidx = dblk * 128 + ni * 16 + frow;
            #pragma unroll
            for (int e = 0; e < 4; ++e) {
                int r = mrow0 + rg * 32 + mi * 16 + (lane >> 4) * 4 + e;
                out[(size_t)r * 512 + cidx] = acc[mi][ni][e];
            }
        }
    }
}

extern "C" void kernel_launch(void* const* d_in, const int* in_sizes, int n_in,
                              void* d_out, int out_size, void* d_ws, size_t ws_size,
                              hipStream_t stream) {
    const float* x  = (const float*)d_in[0];
    const float* Wq = (const float*)d_in[1];
    const float* bq = (const float*)d_in[2];
    const float* Wk = (const float*)d_in[3];
    const float* bk = (const float*)d_in[4];
    (void)bk;
    float* out = (float*)d_out;

    u16* xh  = (u16*)d_ws;
    u16* xl  = xh + (size_t)8388608;
    u16* zh  = xl + (size_t)8388608;
    u16* zl  = zh + (size_t)8388608;
    u16* Mth = zl + (size_t)8388608;
    u16* Mtl = Mth + (size_t)262144;
    u16* Pb  = Mtl + (size_t)262144;
    float* uv = (float*)(Pb + (size_t)16384 * 320);
    u16* xT  = zh;   // alias: zh/zl dead after score_kernel, xT written after

    hipLaunchKernelGGL(split_kernel, dim3(2048), dim3(256), 0, stream, x, xh, xl);
    hipLaunchKernelGGL(mt_kernel, dim3(64), dim3(256), 0, stream, Wk, Wq, Mth, Mtl);
    hipLaunchKernelGGL(u_kernel, dim3(8), dim3(256), 0, stream, Wk, bq, uv);
    hipLaunchKernelGGL(z_kernel, dim3(512), dim3(512), 0, stream,
                       xh, xl, Mth, Mtl, uv, zh, zl);
    hipLaunchKernelGGL(score_kernel, dim3(256), dim3(512), 0, stream,
                       zh, zl, xh, xl, Pb);
    hipLaunchKernelGGL(xt_kernel, dim3(2048), dim3(256), 0, stream, xh, xT);
    hipLaunchKernelGGL(pv_kernel, dim3(256), dim3(512), 0, stream, Pb, xT, out);
}

// Round 6
// 151.441 us; speedup vs baseline: 1.1094x; 1.0991x over previous
//
#include <hip/hip_runtime.h>
#include <hip/hip_bf16.h>

#define S_LEN 4096
#define NEG_INF_F (-1e30f)

typedef __attribute__((ext_vector_type(4))) float f32x4;
typedef __attribute__((ext_vector_type(8))) short s16x8;
typedef unsigned short u16;

static __device__ __forceinline__ u16 f2bf(float f) {
    unsigned u = __builtin_bit_cast(unsigned, f);
    unsigned r = u + 0x7FFFu + ((u >> 16) & 1u);
    return (u16)(r >> 16);
}
static __device__ __forceinline__ float bf2f(u16 h) {
    unsigned u = ((unsigned)h) << 16;
    return __builtin_bit_cast(float, u);
}
static __device__ __forceinline__ void split4(const float4 v, ushort4& hi, ushort4& lo) {
    hi.x = f2bf(v.x); lo.x = f2bf(v.x - bf2f(hi.x));
    hi.y = f2bf(v.y); lo.y = f2bf(v.y - bf2f(hi.y));
    hi.z = f2bf(v.z); lo.z = f2bf(v.z - bf2f(hi.z));
    hi.w = f2bf(v.w); lo.w = f2bf(v.w - bf2f(hi.w));
}
static __device__ __forceinline__ void gl_lds16(const void* g, void* l) {
    __builtin_amdgcn_global_load_lds(
        (const __attribute__((address_space(1))) void*)g,
        (__attribute__((address_space(3))) void*)l, 16, 0, 0);
}
// swizzled u16 offset within a [rows][64 u16] LDS tile
static __device__ __forceinline__ int swz64(int row, int col_u16) {
    return row * 64 + (col_u16 ^ ((row & 7) << 3));
}
// XCD-chunked bijective swizzle for nwg=512 (64 consecutive works per XCD)
static __device__ __forceinline__ int xcd_swz512(int bid) {
    return (bid & 7) * 64 + (bid >> 3);
}

// ---------------- K0: split x -> xh, xl (bf16 hi/lo) ----------------
__global__ __launch_bounds__(256) void split_kernel(
    const float* __restrict__ x, u16* __restrict__ xh, u16* __restrict__ xl) {
    size_t base = (size_t)blockIdx.x * 256 + threadIdx.x;
    #pragma unroll
    for (int i = 0; i < 4; ++i) {
        size_t idx = base + (size_t)i * 524288;
        float4 v = ((const float4*)x)[idx];
        ushort4 hi, lo; split4(v, hi, lo);
        ((ushort4*)xh)[idx] = hi;
        ((ushort4*)xl)[idx] = lo;
    }
}

// ---------------- K1: xT[b][d][s] = xh[b][s][d] ----------------
__global__ __launch_bounds__(256) void xt_kernel(
    const u16* __restrict__ xh, u16* __restrict__ xT) {
    const int bid = blockIdx.x;
    const int dt = bid & 7, st = (bid >> 3) & 63, b = bid >> 9;
    const int s0 = st * 64, d0 = dt * 64;
    __shared__ u16 T[64][72];
    const int tid = threadIdx.x;
    #pragma unroll
    for (int i = 0; i < 2; ++i) {
        int idx = i * 256 + tid;
        int r = idx >> 3, c8 = idx & 7;
        s16x8 v = *(const s16x8*)&xh[(size_t)(b * S_LEN + s0 + r) * 512 + d0 + c8 * 8];
        *(s16x8*)&T[r][c8 * 8] = v;
    }
    __syncthreads();
    #pragma unroll
    for (int i = 0; i < 2; ++i) {
        int idx = i * 256 + tid;
        int dr = idx >> 3, sc = idx & 7;
        s16x8 v;
        #pragma unroll
        for (int t = 0; t < 8; ++t) v[t] = (short)T[sc * 8 + t][dr];
        *(s16x8*)&xT[(size_t)(b * 512 + d0 + dr) * S_LEN + s0 + sc * 8] = v;
    }
}

// ---------------- K2: Mt = Wk^T @ Wq ----------------
__global__ __launch_bounds__(256) void mt_kernel(
    const float* __restrict__ Wk, const float* __restrict__ Wq,
    u16* __restrict__ Mth, u16* __restrict__ Mtl) {
    const int bm = blockIdx.x & 7, bn = blockIdx.x >> 3;
    const int m0 = bm * 64, n0 = bn * 64;
    __shared__ __align__(16) u16 Ath[64 * 72], Atl[64 * 72];
    __shared__ __align__(16) u16 Bth[64 * 72], Btl[64 * 72];
    const int tid = threadIdx.x, lane = tid & 63, w = tid >> 6;
    const int frow = lane & 15, fk = (lane >> 4) * 8;
    f32x4 acc[4] = {};

    for (int h0 = 0; h0 < 512; h0 += 64) {
        #pragma unroll
        for (int i = 0; i < 4; ++i) {
            int idx = i * 256 + tid;
            int h = idx >> 4, c4 = (idx & 15) * 4;
            float4 a = *(const float4*)(Wk + (size_t)(h0 + h) * 512 + m0 + c4);
            ushort4 ahi, alo; split4(a, ahi, alo);
            Ath[(c4 + 0) * 72 + h] = ahi.x; Atl[(c4 + 0) * 72 + h] = alo.x;
            Ath[(c4 + 1) * 72 + h] = ahi.y; Atl[(c4 + 1) * 72 + h] = alo.y;
            Ath[(c4 + 2) * 72 + h] = ahi.z; Atl[(c4 + 2) * 72 + h] = alo.z;
            Ath[(c4 + 3) * 72 + h] = ahi.w; Atl[(c4 + 3) * 72 + h] = alo.w;
            float4 b = *(const float4*)(Wq + (size_t)(h0 + h) * 512 + n0 + c4);
            ushort4 bhi, blo; split4(b, bhi, blo);
            Bth[(c4 + 0) * 72 + h] = bhi.x; Btl[(c4 + 0) * 72 + h] = blo.x;
            Bth[(c4 + 1) * 72 + h] = bhi.y; Btl[(c4 + 1) * 72 + h] = blo.y;
            Bth[(c4 + 2) * 72 + h] = bhi.z; Btl[(c4 + 2) * 72 + h] = blo.z;
            Bth[(c4 + 3) * 72 + h] = bhi.w; Btl[(c4 + 3) * 72 + h] = blo.w;
        }
        __syncthreads();
        #pragma unroll
        for (int kk = 0; kk < 2; ++kk) {
            s16x8 aH = *(const s16x8*)&Ath[(w * 16 + frow) * 72 + kk * 32 + fk];
            s16x8 aL = *(const s16x8*)&Atl[(w * 16 + frow) * 72 + kk * 32 + fk];
            #pragma unroll
            for (int ni = 0; ni < 4; ++ni) {
                s16x8 bH = *(const s16x8*)&Bth[(ni * 16 + frow) * 72 + kk * 32 + fk];
                s16x8 bL = *(const s16x8*)&Btl[(ni * 16 + frow) * 72 + kk * 32 + fk];
                acc[ni] = __builtin_amdgcn_mfma_f32_16x16x32_bf16(aH, bH, acc[ni], 0, 0, 0);
                acc[ni] = __builtin_amdgcn_mfma_f32_16x16x32_bf16(aH, bL, acc[ni], 0, 0, 0);
                acc[ni] = __builtin_amdgcn_mfma_f32_16x16x32_bf16(aL, bH, acc[ni], 0, 0, 0);
            }
        }
        __syncthreads();
    }
    #pragma unroll
    for (int ni = 0; ni < 4; ++ni) {
        int d1 = n0 + ni * 16 + frow;
        #pragma unroll
        for (int e = 0; e < 4; ++e) {
            int d2 = m0 + w * 16 + (lane >> 4) * 4 + e;
            float v = acc[ni][e];
            u16 hi = f2bf(v);
            Mth[(size_t)d2 * 512 + d1] = hi;
            Mtl[(size_t)d2 * 512 + d1] = f2bf(v - bf2f(hi));
        }
    }
}

// ---------------- K3: u = Wk^T @ bq ----------------
__global__ __launch_bounds__(256) void u_kernel(
    const float* __restrict__ Wk, const float* __restrict__ bq,
    float* __restrict__ u) {
    __shared__ float red[4][64];
    const int tid = threadIdx.x, c = tid & 63, hg = tid >> 6;
    const int d2 = blockIdx.x * 64 + c;
    float acc = 0.f;
    for (int h = hg; h < 512; h += 4) acc += Wk[(size_t)h * 512 + d2] * bq[h];
    red[hg][c] = acc;
    __syncthreads();
    if (hg == 0) u[d2] = red[0][c] + red[1][c] + red[2][c] + red[3][c];
}

// ---------------- K4: z = x @ Mt^T + u (single-buffer, 2 blocks/CU) ----------------
// grid 512 = 128 m-tiles x 4 n-tiles (XCD-swizzled). block 512 (8 waves: 2 rg x 4 cg).
__global__ __launch_bounds__(512) void z_kernel(
    const u16* __restrict__ xh, const u16* __restrict__ xl,
    const u16* __restrict__ Mth, const u16* __restrict__ Mtl,
    const float* __restrict__ u, u16* __restrict__ zh, u16* __restrict__ zl) {
    const int w_ = xcd_swz512((int)blockIdx.x);
    const int bm = w_ >> 2, bn = w_ & 3;
    const int m0 = bm * 128, n0 = bn * 128;
    __shared__ __align__(16) u16 Ah[128 * 64], Al[128 * 64];
    __shared__ __align__(16) u16 Bh[128 * 64], Bl[128 * 64];
    const int tid = threadIdx.x, lane = tid & 63, w = tid >> 6;
    const int rg = w >> 2, cg = w & 3;
    const int frow = lane & 15, fk = (lane >> 4) * 8;
    f32x4 acc[4][2] = {};

    for (int k0 = 0; k0 < 512; k0 += 64) {
        #pragma unroll
        for (int i = 0; i < 2; ++i) {
            int idx = i * 512 + tid;          // 1024 chunks per array
            int r = idx >> 3, c = idx & 7;
            int sc = (c ^ (r & 7)) * 8;
            gl_lds16(xh + (size_t)(m0 + r) * 512 + k0 + sc, &Ah[idx * 8]);
            gl_lds16(xl + (size_t)(m0 + r) * 512 + k0 + sc, &Al[idx * 8]);
            gl_lds16(Mth + (size_t)(n0 + r) * 512 + k0 + sc, &Bh[idx * 8]);
            gl_lds16(Mtl + (size_t)(n0 + r) * 512 + k0 + sc, &Bl[idx * 8]);
        }
        __syncthreads();
        #pragma unroll
        for (int kk = 0; kk < 2; ++kk) {
            s16x8 aH[4], aL[4], bH[2], bL[2];
            #pragma unroll
            for (int mi = 0; mi < 4; ++mi) {
                int row = rg * 64 + mi * 16 + frow;
                aH[mi] = *(const s16x8*)&Ah[swz64(row, kk * 32 + fk)];
                aL[mi] = *(const s16x8*)&Al[swz64(row, kk * 32 + fk)];
            }
            #pragma unroll
            for (int ni = 0; ni < 2; ++ni) {
                int row = cg * 32 + ni * 16 + frow;
                bH[ni] = *(const s16x8*)&Bh[swz64(row, kk * 32 + fk)];
                bL[ni] = *(const s16x8*)&Bl[swz64(row, kk * 32 + fk)];
            }
            #pragma unroll
            for (int mi = 0; mi < 4; ++mi)
                #pragma unroll
                for (int ni = 0; ni < 2; ++ni) {
                    acc[mi][ni] = __builtin_amdgcn_mfma_f32_16x16x32_bf16(aH[mi], bH[ni], acc[mi][ni], 0, 0, 0);
                    acc[mi][ni] = __builtin_amdgcn_mfma_f32_16x16x32_bf16(aH[mi], bL[ni], acc[mi][ni], 0, 0, 0);
                    acc[mi][ni] = __builtin_amdgcn_mfma_f32_16x16x32_bf16(aL[mi], bH[ni], acc[mi][ni], 0, 0, 0);
                }
        }
        __syncthreads();
    }
    #pragma unroll
    for (int ni = 0; ni < 2; ++ni) {
        int col = n0 + cg * 32 + ni * 16 + frow;
        float uv = u[col];
        #pragma unroll
        for (int mi = 0; mi < 4; ++mi) {
            int rbase = m0 + rg * 64 + mi * 16 + (lane >> 4) * 4;
            #pragma unroll
            for (int e = 0; e < 4; ++e) {
                float v = acc[mi][ni][e] + uv;
                u16 hi = f2bf(v);
                zh[(size_t)(rbase + e) * 512 + col] = hi;
                zl[(size_t)(rbase + e) * 512 + col] = f2bf(v - bf2f(hi));
            }
        }
    }
}

// ---------------- K5: banded scores + softmax -> P bf16 ----------------
// grid 512 = 4b x 128 32-row tiles (XCD-swizzled). block 512 (8 waves: 2 row-groups x 4 quarters).
// Window: 288 rows, jj_s = j - (i0-128). Valid per row r: 1 <= jj_s - r <= 255.
// Row group g (rows [g*16,g*16+16)): valid tiles [g, g+16] (17), split 4/4/4/5 across quarters.
// P indexed in the 64-row-tile frame: jj_pv = jj_s + 32*(it2&1).
__global__ __launch_bounds__(512, 4) void score_kernel(
    const u16* __restrict__ zh, const u16* __restrict__ zl,
    const u16* __restrict__ xh, const u16* __restrict__ xl,
    u16* __restrict__ P) {
    const int w_ = xcd_swz512((int)blockIdx.x);
    const int b = w_ >> 7, it2 = w_ & 127;
    const int i0 = it2 * 32, j0 = i0 - 128;
    const int mrow0 = b * S_LEN + i0;
    const int off = (it2 & 1) * 32;
    __shared__ __align__(16) u16 Kh[288 * 64], Kl[288 * 64];   // 72 KB total

    const int tid = threadIdx.x, lane = tid & 63, w = tid >> 6;
    const int g = w >> 2, q = w & 3;
    const int frow = lane & 15, fk = (lane >> 4) * 8;
    const int tstart = g + q * 4;
    const int nt = (q == 3) ? 5 : 4;
    const size_t qoff = (size_t)(mrow0 + g * 16 + frow) * 512;

    f32x4 acc[5] = {};

    for (int t = 0; t < 8; ++t) {
        const int k0 = t * 64;
        // Q fragments: global -> registers (z is L2-resident)
        s16x8 aH0 = *(const s16x8*)(zh + qoff + k0 + fk);
        s16x8 aH1 = *(const s16x8*)(zh + qoff + k0 + 32 + fk);
        s16x8 aL0 = *(const s16x8*)(zl + qoff + k0 + fk);
        s16x8 aL1 = *(const s16x8*)(zl + qoff + k0 + 32 + fk);
        // K window: 2304 chunks per array; 2304%64==0 so each wave is side-uniform
        #pragma unroll
        for (int i = 0; i < 9; ++i) {
            int f = i * 512 + tid;
            int idx = (f < 2304) ? f : f - 2304;
            int r = idx >> 3, c = idx & 7;
            int sc = (c ^ (r & 7)) * 8;
            int j = min(max(j0 + r, 0), S_LEN - 1);
            if (f < 2304)
                gl_lds16(xh + (size_t)(b * S_LEN + j) * 512 + k0 + sc, &Kh[idx * 8]);
            else
                gl_lds16(xl + (size_t)(b * S_LEN + j) * 512 + k0 + sc, &Kl[idx * 8]);
        }
        __syncthreads();
        #pragma unroll
        for (int kk = 0; kk < 2; ++kk) {
            s16x8 aH = kk ? aH1 : aH0;
            s16x8 aL = kk ? aL1 : aL0;
            #pragma unroll
            for (int tt = 0; tt < 5; ++tt) {
                if (tt < nt) {
                    int krow = (tstart + tt) * 16 + frow;
                    s16x8 bH = *(const s16x8*)&Kh[swz64(krow, kk * 32 + fk)];
                    s16x8 bL = *(const s16x8*)&Kl[swz64(krow, kk * 32 + fk)];
                    acc[tt] = __builtin_amdgcn_mfma_f32_16x16x32_bf16(aH, bH, acc[tt], 0, 0, 0);
                    acc[tt] = __builtin_amdgcn_mfma_f32_16x16x32_bf16(aH, bL, acc[tt], 0, 0, 0);
                    acc[tt] = __builtin_amdgcn_mfma_f32_16x16x32_bf16(aL, bH, acc[tt], 0, 0, 0);
                }
            }
        }
        __syncthreads();
    }

    // ---- softmax; stats [32][4] aliased onto dead K buffers ----
    float* sred_max = (float*)Kh;
    float* sred_sum = (float*)Kl;
    const int rq = (lane >> 4) * 4;

    #pragma unroll
    for (int e = 0; e < 4; ++e) {
        int r = g * 16 + rq + e;
        float m = NEG_INF_F;
        #pragma unroll
        for (int tt = 0; tt < 5; ++tt) {
            if (tt < nt) {
                int jj = (tstart + tt) * 16 + frow;
                int dj = jj - r, j = j0 + jj;
                if (dj >= 1 && dj <= 255 && j >= 0 && j < S_LEN) m = fmaxf(m, acc[tt][e]);
            }
        }
        #pragma unroll
        for (int d = 1; d < 16; d <<= 1) m = fmaxf(m, __shfl_xor(m, d));
        if (frow == 0) sred_max[r * 4 + q] = m;
    }
    __syncthreads();
    float sh[4];
    #pragma unroll
    for (int e = 0; e < 4; ++e) {
        int r = g * 16 + rq + e;
        float mx = fmaxf(fmaxf(sred_max[r * 4], sred_max[r * 4 + 1]),
                         fmaxf(sred_max[r * 4 + 2], sred_max[r * 4 + 3]));
        float s = 0.f;
        #pragma unroll
        for (int tt = 0; tt < 5; ++tt) {
            float pv = 0.f;
            if (tt < nt) {
                int jj = (tstart + tt) * 16 + frow;
                int dj = jj - r, j = j0 + jj;
                bool valid = (dj >= 1 && dj <= 255 && j >= 0 && j < S_LEN);
                pv = valid ? __expf(acc[tt][e] - mx) : 0.f;
            }
            acc[tt][e] = pv;
            s += pv;
        }
        #pragma unroll
        for (int d = 1; d < 16; d <<= 1) s += __shfl_xor(s, d);
        sh[e] = s;
    }
    if (frow == 0) {
        #pragma unroll
        for (int e = 0; e < 4; ++e) sred_sum[(g * 16 + rq + e) * 4 + q] = sh[e];
    }
    __syncthreads();
    float invv[4];
    #pragma unroll
    for (int e = 0; e < 4; ++e) {
        int r = g * 16 + rq + e;
        invv[e] = 1.f / (sred_sum[r * 4] + sred_sum[r * 4 + 1] +
                         sred_sum[r * 4 + 2] + sred_sum[r * 4 + 3]);
    }
    // valid (and in-tile masked-zero) writes
    #pragma unroll
    for (int tt = 0; tt < 5; ++tt) {
        if (tt < nt) {
            int t = tstart + tt;
            #pragma unroll
            for (int e = 0; e < 4; ++e) {
                int r = g * 16 + rq + e;
                P[(size_t)(mrow0 + r) * 320 + off + t * 16 + frow] = f2bf(acc[tt][e] * invv[e]);
            }
        }
    }
    // band-complement zero-fill in the pv frame: left [0, rr+1), right [rr+256, 320).
    // Overlaps only this row-group's q0/q3 tile writes (which are masked zeros) -> benign.
    if (q == 0) {
        #pragma unroll
        for (int e = 0; e < 4; ++e) {
            int r = g * 16 + rq + e;
            int rr = off + r;
            size_t rowoff = (size_t)(mrow0 + r) * 320;
            for (int c = frow; c <= rr; c += 16) P[rowoff + c] = 0;
        }
    }
    if (q == 3) {
        #pragma unroll
        for (int e = 0; e < 4; ++e) {
            int r = g * 16 + rq + e;
            int rr = off + r;
            size_t rowoff = (size_t)(mrow0 + r) * 320;
            for (int c = rr + 256 + frow; c < 320; c += 16) P[rowoff + c] = 0;
        }
    }
}

// ---------------- K6: out = P @ x_window (uses xT, d-split) ----------------
// grid 512 = 4b x 64 row-tiles x 2 d-halves (XCD-swizzled). block 512 (8 waves: 2 rg x 4 dblk).
__global__ __launch_bounds__(512) void pv_kernel(
    const u16* __restrict__ P, const u16* __restrict__ xT,
    float* __restrict__ out) {
    const int w_ = xcd_swz512((int)blockIdx.x);
    const int b = w_ >> 7, it = (w_ >> 1) & 63, dh = w_ & 1;
    const int i0 = it * 64, j0 = i0 - 128, d0 = dh * 256;
    const int mrow0 = b * S_LEN + i0;
    __shared__ __align__(16) u16 Ph[64 * 64];    // 8 KB
    __shared__ __align__(16) u16 XT[256 * 64];   // 32 KB
    const int tid = threadIdx.x, lane = tid & 63, w = tid >> 6;
    const int rg = w >> 2, dblk = w & 3;
    const int frow = lane & 15, fkb = (lane >> 4) * 8;
    f32x4 acc[2][4] = {};

    for (int k0 = 0; k0 < 320; k0 += 64) {
        #pragma unroll
        for (int i = 0; i < 5; ++i) {
            int f = i * 512 + tid;
            if (f < 512) {
                int r = f >> 3, c = f & 7;
                gl_lds16(P + (size_t)(mrow0 + r) * 320 + k0 + (c ^ (r & 7)) * 8,
                         &Ph[f * 8]);
            } else {
                int idx = f - 512;                // 2048 chunks (256 d-rows x 8)
                int dr = idx >> 3, c = idx & 7;
                int jb = j0 + k0 + (c ^ (dr & 7)) * 8;
                jb = min(max(jb, 0), S_LEN - 8);  // clamped edges: P==0 there
                gl_lds16(xT + (size_t)(b * 512 + d0 + dr) * S_LEN + jb, &XT[idx * 8]);
            }
        }
        __syncthreads();
        #pragma unroll
        for (int kk = 0; kk < 2; ++kk) {
            s16x8 a[2];
            #pragma unroll
            for (int mi = 0; mi < 2; ++mi) {
                int row = rg * 32 + mi * 16 + frow;
                a[mi] = *(const s16x8*)&Ph[swz64(row, kk * 32 + fkb)];
            }
            #pragma unroll
            for (int ni = 0; ni < 4; ++ni) {
                int drow = dblk * 64 + ni * 16 + frow;
                s16x8 bf = *(const s16x8*)&XT[swz64(drow, kk * 32 + fkb)];
                acc[0][ni] = __builtin_amdgcn_mfma_f32_16x16x32_bf16(a[0], bf, acc[0][ni], 0, 0, 0);
                acc[1][ni] = __builtin_amdgcn_mfma_f32_16x16x32_bf16(a[1], bf, acc[1][ni], 0, 0, 0);
            }
        }
        __syncthreads();
    }
    #pragma unroll
    for (int mi = 0; mi < 2; ++mi) {
        #pragma unroll
        for (int ni = 0; ni < 4; ++ni) {
            int cidx = d0 + dblk * 64 + ni * 16 + frow;
            #pragma unroll
            for (int e = 0; e < 4; ++e) {
                int r = mrow0 + rg * 32 + mi * 16 + (lane >> 4) * 4 + e;
                out[(size_t)r * 512 + cidx] = acc[mi][ni][e];
            }
        }
    }
}

extern "C" void kernel_launch(void* const* d_in, const int* in_sizes, int n_in,
                              void* d_out, int out_size, void* d_ws, size_t ws_size,
                              hipStream_t stream) {
    const float* x  = (const float*)d_in[0];
    const float* Wq = (const float*)d_in[1];
    const float* bq = (const float*)d_in[2];
    const float* Wk = (const float*)d_in[3];
    const float* bk = (const float*)d_in[4];
    (void)bk;
    float* out = (float*)d_out;

    u16* xh  = (u16*)d_ws;
    u16* xl  = xh + (size_t)8388608;
    u16* zh  = xl + (size_t)8388608;
    u16* zl  = zh + (size_t)8388608;
    u16* Mth = zl + (size_t)8388608;
    u16* Mtl = Mth + (size_t)262144;
    u16* Pb  = Mtl + (size_t)262144;
    float* uv = (float*)(Pb + (size_t)16384 * 320);
    u16* xT  = zh;   // alias: zh/zl dead after score_kernel, xT written after

    hipLaunchKernelGGL(split_kernel, dim3(2048), dim3(256), 0, stream, x, xh, xl);
    hipLaunchKernelGGL(mt_kernel, dim3(64), dim3(256), 0, stream, Wk, Wq, Mth, Mtl);
    hipLaunchKernelGGL(u_kernel, dim3(8), dim3(256), 0, stream, Wk, bq, uv);
    hipLaunchKernelGGL(z_kernel, dim3(512), dim3(512), 0, stream,
                       xh, xl, Mth, Mtl, uv, zh, zl);
    hipLaunchKernelGGL(score_kernel, dim3(512), dim3(512), 0, stream,
                       zh, zl, xh, xl, Pb);
    hipLaunchKernelGGL(xt_kernel, dim3(2048), dim3(256), 0, stream, xh, xT);
    hipLaunchKernelGGL(pv_kernel, dim3(512), dim3(512), 0, stream, Pb, xT, out);
}

// Round 7
// 141.188 us; speedup vs baseline: 1.1899x; 1.0726x over previous
//
#include <hip/hip_runtime.h>
#include <hip/hip_bf16.h>

#define S_LEN 4096
#define NEG_INF_F (-1e30f)

typedef __attribute__((ext_vector_type(4))) float f32x4;
typedef __attribute__((ext_vector_type(8))) short s16x8;
typedef unsigned short u16;

static __device__ __forceinline__ u16 f2bf(float f) {
    unsigned u = __builtin_bit_cast(unsigned, f);
    unsigned r = u + 0x7FFFu + ((u >> 16) & 1u);
    return (u16)(r >> 16);
}
static __device__ __forceinline__ float bf2f(u16 h) {
    unsigned u = ((unsigned)h) << 16;
    return __builtin_bit_cast(float, u);
}
static __device__ __forceinline__ void split4(const float4 v, ushort4& hi, ushort4& lo) {
    hi.x = f2bf(v.x); lo.x = f2bf(v.x - bf2f(hi.x));
    hi.y = f2bf(v.y); lo.y = f2bf(v.y - bf2f(hi.y));
    hi.z = f2bf(v.z); lo.z = f2bf(v.z - bf2f(hi.z));
    hi.w = f2bf(v.w); lo.w = f2bf(v.w - bf2f(hi.w));
}
static __device__ __forceinline__ void gl_lds16(const void* g, void* l) {
    __builtin_amdgcn_global_load_lds(
        (const __attribute__((address_space(1))) void*)g,
        (__attribute__((address_space(3))) void*)l, 16, 0, 0);
}
// swizzled u16 offset within a [rows][64 u16] LDS tile
static __device__ __forceinline__ int swz64(int row, int col_u16) {
    return row * 64 + (col_u16 ^ ((row & 7) << 3));
}
// swizzled u16 offset within a [rows][320 u16] LDS tile (XOR in octet low bits)
static __device__ __forceinline__ int swz320(int row, int col_u16) {
    return row * 320 + (col_u16 ^ ((row & 7) << 3));
}
// XCD-chunked bijective swizzle for nwg=512
static __device__ __forceinline__ int xcd_swz512(int bid) {
    return (bid & 7) * 64 + (bid >> 3);
}

// ---------------- K0: split x -> xh, xl AND xT (fused transpose) ----------------
// grid 2048 = 4b x 64 s-tiles x 8 d-tiles. block 256.
__global__ __launch_bounds__(256) void split_xt_kernel(
    const float* __restrict__ x, u16* __restrict__ xh, u16* __restrict__ xl,
    u16* __restrict__ xT) {
    const int bid = blockIdx.x;
    const int dt = bid & 7, st = (bid >> 3) & 63, b = bid >> 9;
    const int s0 = st * 64, d0 = dt * 64;
    __shared__ u16 T[64][72];
    const int tid = threadIdx.x;
    #pragma unroll
    for (int i = 0; i < 4; ++i) {
        int idx = i * 256 + tid;            // 1024 float4 slots (64 rows x 16)
        int r = idx >> 4, c4 = (idx & 15) * 4;
        float4 v = *(const float4*)(x + (size_t)(b * S_LEN + s0 + r) * 512 + d0 + c4);
        ushort4 hi, lo; split4(v, hi, lo);
        *(ushort4*)(xh + (size_t)(b * S_LEN + s0 + r) * 512 + d0 + c4) = hi;
        *(ushort4*)(xl + (size_t)(b * S_LEN + s0 + r) * 512 + d0 + c4) = lo;
        *(ushort4*)&T[r][c4] = hi;
    }
    __syncthreads();
    #pragma unroll
    for (int i = 0; i < 2; ++i) {
        int idx = i * 256 + tid;            // 512 chunks (64 d-rows x 8)
        int dr = idx >> 3, sc = idx & 7;
        s16x8 v;
        #pragma unroll
        for (int t = 0; t < 8; ++t) v[t] = (short)T[sc * 8 + t][dr];
        *(s16x8*)&xT[(size_t)(b * 512 + d0 + dr) * S_LEN + s0 + sc * 8] = v;
    }
}

// ---------------- K1: Mt = Wk^T @ Wq ----------------
__global__ __launch_bounds__(256) void mt_kernel(
    const float* __restrict__ Wk, const float* __restrict__ Wq,
    u16* __restrict__ Mth, u16* __restrict__ Mtl) {
    const int bm = blockIdx.x & 7, bn = blockIdx.x >> 3;
    const int m0 = bm * 64, n0 = bn * 64;
    __shared__ __align__(16) u16 Ath[64 * 72], Atl[64 * 72];
    __shared__ __align__(16) u16 Bth[64 * 72], Btl[64 * 72];
    const int tid = threadIdx.x, lane = tid & 63, w = tid >> 6;
    const int frow = lane & 15, fk = (lane >> 4) * 8;
    f32x4 acc[4] = {};

    for (int h0 = 0; h0 < 512; h0 += 64) {
        #pragma unroll
        for (int i = 0; i < 4; ++i) {
            int idx = i * 256 + tid;
            int h = idx >> 4, c4 = (idx & 15) * 4;
            float4 a = *(const float4*)(Wk + (size_t)(h0 + h) * 512 + m0 + c4);
            ushort4 ahi, alo; split4(a, ahi, alo);
            Ath[(c4 + 0) * 72 + h] = ahi.x; Atl[(c4 + 0) * 72 + h] = alo.x;
            Ath[(c4 + 1) * 72 + h] = ahi.y; Atl[(c4 + 1) * 72 + h] = alo.y;
            Ath[(c4 + 2) * 72 + h] = ahi.z; Atl[(c4 + 2) * 72 + h] = alo.z;
            Ath[(c4 + 3) * 72 + h] = ahi.w; Atl[(c4 + 3) * 72 + h] = alo.w;
            float4 b = *(const float4*)(Wq + (size_t)(h0 + h) * 512 + n0 + c4);
            ushort4 bhi, blo; split4(b, bhi, blo);
            Bth[(c4 + 0) * 72 + h] = bhi.x; Btl[(c4 + 0) * 72 + h] = blo.x;
            Bth[(c4 + 1) * 72 + h] = bhi.y; Btl[(c4 + 1) * 72 + h] = blo.y;
            Bth[(c4 + 2) * 72 + h] = bhi.z; Btl[(c4 + 2) * 72 + h] = blo.z;
            Bth[(c4 + 3) * 72 + h] = bhi.w; Btl[(c4 + 3) * 72 + h] = blo.w;
        }
        __syncthreads();
        #pragma unroll
        for (int kk = 0; kk < 2; ++kk) {
            s16x8 aH = *(const s16x8*)&Ath[(w * 16 + frow) * 72 + kk * 32 + fk];
            s16x8 aL = *(const s16x8*)&Atl[(w * 16 + frow) * 72 + kk * 32 + fk];
            #pragma unroll
            for (int ni = 0; ni < 4; ++ni) {
                s16x8 bH = *(const s16x8*)&Bth[(ni * 16 + frow) * 72 + kk * 32 + fk];
                s16x8 bL = *(const s16x8*)&Btl[(ni * 16 + frow) * 72 + kk * 32 + fk];
                acc[ni] = __builtin_amdgcn_mfma_f32_16x16x32_bf16(aH, bH, acc[ni], 0, 0, 0);
                acc[ni] = __builtin_amdgcn_mfma_f32_16x16x32_bf16(aH, bL, acc[ni], 0, 0, 0);
                acc[ni] = __builtin_amdgcn_mfma_f32_16x16x32_bf16(aL, bH, acc[ni], 0, 0, 0);
            }
        }
        __syncthreads();
    }
    #pragma unroll
    for (int ni = 0; ni < 4; ++ni) {
        int d1 = n0 + ni * 16 + frow;
        #pragma unroll
        for (int e = 0; e < 4; ++e) {
            int d2 = m0 + w * 16 + (lane >> 4) * 4 + e;
            float v = acc[ni][e];
            u16 hi = f2bf(v);
            Mth[(size_t)d2 * 512 + d1] = hi;
            Mtl[(size_t)d2 * 512 + d1] = f2bf(v - bf2f(hi));
        }
    }
}

// ---------------- K2: u = Wk^T @ bq ----------------
__global__ __launch_bounds__(256) void u_kernel(
    const float* __restrict__ Wk, const float* __restrict__ bq,
    float* __restrict__ u) {
    __shared__ float red[4][64];
    const int tid = threadIdx.x, c = tid & 63, hg = tid >> 6;
    const int d2 = blockIdx.x * 64 + c;
    float acc = 0.f;
    for (int h = hg; h < 512; h += 4) acc += Wk[(size_t)h * 512 + d2] * bq[h];
    red[hg][c] = acc;
    __syncthreads();
    if (hg == 0) u[d2] = red[0][c] + red[1][c] + red[2][c] + red[3][c];
}

// ---------------- K3: z = x @ Mt^T + u ----------------
// grid 512 = 128 m-tiles x 4 n-tiles (XCD-swizzled). block 512 (8 waves: 2 rg x 4 cg).
__global__ __launch_bounds__(512) void z_kernel(
    const u16* __restrict__ xh, const u16* __restrict__ xl,
    const u16* __restrict__ Mth, const u16* __restrict__ Mtl,
    const float* __restrict__ u, u16* __restrict__ zh, u16* __restrict__ zl) {
    const int w_ = xcd_swz512((int)blockIdx.x);
    const int bm = w_ >> 2, bn = w_ & 3;
    const int m0 = bm * 128, n0 = bn * 128;
    __shared__ __align__(16) u16 Ah[128 * 64], Al[128 * 64];
    __shared__ __align__(16) u16 Bh[128 * 64], Bl[128 * 64];
    const int tid = threadIdx.x, lane = tid & 63, w = tid >> 6;
    const int rg = w >> 2, cg = w & 3;
    const int frow = lane & 15, fk = (lane >> 4) * 8;
    f32x4 acc[4][2] = {};

    for (int k0 = 0; k0 < 512; k0 += 64) {
        #pragma unroll
        for (int i = 0; i < 2; ++i) {
            int idx = i * 512 + tid;          // 1024 chunks per array
            int r = idx >> 3, c = idx & 7;
            int sc = (c ^ (r & 7)) * 8;
            gl_lds16(xh + (size_t)(m0 + r) * 512 + k0 + sc, &Ah[idx * 8]);
            gl_lds16(xl + (size_t)(m0 + r) * 512 + k0 + sc, &Al[idx * 8]);
            gl_lds16(Mth + (size_t)(n0 + r) * 512 + k0 + sc, &Bh[idx * 8]);
            gl_lds16(Mtl + (size_t)(n0 + r) * 512 + k0 + sc, &Bl[idx * 8]);
        }
        __syncthreads();
        #pragma unroll
        for (int kk = 0; kk < 2; ++kk) {
            s16x8 aH[4], aL[4], bH[2], bL[2];
            #pragma unroll
            for (int mi = 0; mi < 4; ++mi) {
                int row = rg * 64 + mi * 16 + frow;
                aH[mi] = *(const s16x8*)&Ah[swz64(row, kk * 32 + fk)];
                aL[mi] = *(const s16x8*)&Al[swz64(row, kk * 32 + fk)];
            }
            #pragma unroll
            for (int ni = 0; ni < 2; ++ni) {
                int row = cg * 32 + ni * 16 + frow;
                bH[ni] = *(const s16x8*)&Bh[swz64(row, kk * 32 + fk)];
                bL[ni] = *(const s16x8*)&Bl[swz64(row, kk * 32 + fk)];
            }
            #pragma unroll
            for (int mi = 0; mi < 4; ++mi)
                #pragma unroll
                for (int ni = 0; ni < 2; ++ni) {
                    acc[mi][ni] = __builtin_amdgcn_mfma_f32_16x16x32_bf16(aH[mi], bH[ni], acc[mi][ni], 0, 0, 0);
                    acc[mi][ni] = __builtin_amdgcn_mfma_f32_16x16x32_bf16(aH[mi], bL[ni], acc[mi][ni], 0, 0, 0);
                    acc[mi][ni] = __builtin_amdgcn_mfma_f32_16x16x32_bf16(aL[mi], bH[ni], acc[mi][ni], 0, 0, 0);
                }
        }
        __syncthreads();
    }
    #pragma unroll
    for (int ni = 0; ni < 2; ++ni) {
        int col = n0 + cg * 32 + ni * 16 + frow;
        float uv = u[col];
        #pragma unroll
        for (int mi = 0; mi < 4; ++mi) {
            int rbase = m0 + rg * 64 + mi * 16 + (lane >> 4) * 4;
            #pragma unroll
            for (int e = 0; e < 4; ++e) {
                float v = acc[mi][ni][e] + uv;
                u16 hi = f2bf(v);
                zh[(size_t)(rbase + e) * 512 + col] = hi;
                zl[(size_t)(rbase + e) * 512 + col] = f2bf(v - bf2f(hi));
            }
        }
    }
}

// ---------------- K4: fused banded attention: scores + softmax + PV ----------------
// grid 512 = 4b x 128 32-row tiles (XCD-swizzled). block 512 (8 waves).
// Phase 1 (QK^T): waves = 2 row-groups x 4 window-quarters; window 288 rows.
// Phase 2: softmax, P kept in LDS (32x320 bf16, swizzled), missing tile zeroed.
// Phase 3 (PV): 8 steps of 64 d-rows of xT staged to LDS; waves = 2 rg x 4 d-tiles.
__global__ __launch_bounds__(512, 4) void attn_kernel(
    const u16* __restrict__ zh, const u16* __restrict__ zl,
    const u16* __restrict__ xh, const u16* __restrict__ xl,
    const u16* __restrict__ xT, float* __restrict__ out) {
    const int w_ = xcd_swz512((int)blockIdx.x);
    const int b = w_ >> 7, it2 = w_ & 127;
    const int i0 = it2 * 32, j0 = i0 - 128;
    const int mrow0 = b * S_LEN + i0;

    __shared__ __align__(16) u16 smem[36864];       // 72 KB
    u16* Kh = smem;                                  // [288*64]
    u16* Kl = smem + 18432;                          // [288*64]
    u16* PL = smem;                                  // [32*320] (aliases Kh, used after)
    u16* VL = smem + 10240;                          // [64*320] (aliases Kh/Kl tail)
    __shared__ float sred_max[32 * 4], sred_sum[32 * 4];

    const int tid = threadIdx.x, lane = tid & 63, w = tid >> 6;
    const int g = w >> 2, q = w & 3;
    const int frow = lane & 15, fk = (lane >> 4) * 8;
    const int tstart = g + q * 4;
    const int nt = (q == 3) ? 5 : 4;
    const size_t qoff = (size_t)(mrow0 + g * 16 + frow) * 512;

    f32x4 acc[5] = {};

    // ---- phase 1: QK^T over K=512 (8 chunks of 64) ----
    for (int t = 0; t < 8; ++t) {
        const int k0 = t * 64;
        s16x8 aH0 = *(const s16x8*)(zh + qoff + k0 + fk);
        s16x8 aH1 = *(const s16x8*)(zh + qoff + k0 + 32 + fk);
        s16x8 aL0 = *(const s16x8*)(zl + qoff + k0 + fk);
        s16x8 aL1 = *(const s16x8*)(zl + qoff + k0 + 32 + fk);
        #pragma unroll
        for (int i = 0; i < 9; ++i) {
            int f = i * 512 + tid;
            int idx = (f < 2304) ? f : f - 2304;
            int r = idx >> 3, c = idx & 7;
            int sc = (c ^ (r & 7)) * 8;
            int j = min(max(j0 + r, 0), S_LEN - 1);
            if (f < 2304)
                gl_lds16(xh + (size_t)(b * S_LEN + j) * 512 + k0 + sc, &Kh[idx * 8]);
            else
                gl_lds16(xl + (size_t)(b * S_LEN + j) * 512 + k0 + sc, &Kl[idx * 8]);
        }
        __syncthreads();
        #pragma unroll
        for (int kk = 0; kk < 2; ++kk) {
            s16x8 aH = kk ? aH1 : aH0;
            s16x8 aL = kk ? aL1 : aL0;
            #pragma unroll
            for (int tt = 0; tt < 5; ++tt) {
                if (tt < nt) {
                    int krow = (tstart + tt) * 16 + frow;
                    s16x8 bH = *(const s16x8*)&Kh[swz64(krow, kk * 32 + fk)];
                    s16x8 bL = *(const s16x8*)&Kl[swz64(krow, kk * 32 + fk)];
                    acc[tt] = __builtin_amdgcn_mfma_f32_16x16x32_bf16(aH, bH, acc[tt], 0, 0, 0);
                    acc[tt] = __builtin_amdgcn_mfma_f32_16x16x32_bf16(aH, bL, acc[tt], 0, 0, 0);
                    acc[tt] = __builtin_amdgcn_mfma_f32_16x16x32_bf16(aL, bH, acc[tt], 0, 0, 0);
                }
            }
        }
        __syncthreads();
    }

    // ---- phase 2: softmax ----
    const int rq = (lane >> 4) * 4;
    #pragma unroll
    for (int e = 0; e < 4; ++e) {
        int r = g * 16 + rq + e;
        float m = NEG_INF_F;
        #pragma unroll
        for (int tt = 0; tt < 5; ++tt) {
            if (tt < nt) {
                int jj = (tstart + tt) * 16 + frow;
                int dj = jj - r, j = j0 + jj;
                if (dj >= 1 && dj <= 255 && j >= 0 && j < S_LEN) m = fmaxf(m, acc[tt][e]);
            }
        }
        #pragma unroll
        for (int d = 1; d < 16; d <<= 1) m = fmaxf(m, __shfl_xor(m, d));
        if (frow == 0) sred_max[r * 4 + q] = m;
    }
    __syncthreads();
    float sh[4];
    #pragma unroll
    for (int e = 0; e < 4; ++e) {
        int r = g * 16 + rq + e;
        float mx = fmaxf(fmaxf(sred_max[r * 4], sred_max[r * 4 + 1]),
                         fmaxf(sred_max[r * 4 + 2], sred_max[r * 4 + 3]));
        float s = 0.f;
        #pragma unroll
        for (int tt = 0; tt < 5; ++tt) {
            float pv = 0.f;
            if (tt < nt) {
                int jj = (tstart + tt) * 16 + frow;
                int dj = jj - r, j = j0 + jj;
                bool valid = (dj >= 1 && dj <= 255 && j >= 0 && j < S_LEN);
                pv = valid ? __expf(acc[tt][e] - mx) : 0.f;
            }
            acc[tt][e] = pv;
            s += pv;
        }
        #pragma unroll
        for (int d = 1; d < 16; d <<= 1) s += __shfl_xor(s, d);
        sh[e] = s;
    }
    if (frow == 0) {
        #pragma unroll
        for (int e = 0; e < 4; ++e) sred_sum[(g * 16 + rq + e) * 4 + q] = sh[e];
    }
    __syncthreads();
    float invv[4];
    #pragma unroll
    for (int e = 0; e < 4; ++e) {
        int r = g * 16 + rq + e;
        invv[e] = 1.f / (sred_sum[r * 4] + sred_sum[r * 4 + 1] +
                         sred_sum[r * 4 + 2] + sred_sum[r * 4 + 3]);
    }
    // write normalized P to LDS (K buffers dead; all K reads completed above)
    #pragma unroll
    for (int tt = 0; tt < 5; ++tt) {
        if (tt < nt) {
            int t = tstart + tt;
            #pragma unroll
            for (int e = 0; e < 4; ++e) {
                int r = g * 16 + rq + e;
                PL[swz320(r, t * 16 + frow)] = f2bf(acc[tt][e] * invv[e]);
            }
        }
    }
    // zero the one tile this row-group's quarters never wrote (g=0 -> tile 17, g=1 -> tile 0)
    if (q == 0) {
        int t = (g == 0) ? 17 : 0;
        int r = g * 16 + frow;
        #pragma unroll
        for (int e2 = 0; e2 < 4; ++e2)
            PL[swz320(r, t * 16 + (lane >> 4) * 4 + e2)] = 0;
    }

    // ---- phase 3: PV. 8 steps x 64 d-rows of xT staged into VL ----
    for (int ds = 0; ds < 8; ++ds) {
        const int d0 = ds * 64;
        #pragma unroll
        for (int i = 0; i < 5; ++i) {
            int idx = i * 512 + tid;            // 2560 chunks (64 rows x 40)
            int dr = idx / 40, c8 = idx - dr * 40;
            int src = c8 ^ (dr & 7);
            int jb = j0 + src * 8;
            jb = min(max(jb, 0), S_LEN - 8);    // clamped cols have P==0
            gl_lds16(xT + (size_t)(b * 512 + d0 + dr) * S_LEN + jb, &VL[idx * 8]);
        }
        __syncthreads();
        f32x4 po = {};
        #pragma unroll
        for (int jt = 0; jt < 9; ++jt) {
            s16x8 a = *(const s16x8*)&PL[swz320(g * 16 + frow, jt * 32 + fk)];
            s16x8 bv = *(const s16x8*)&VL[swz320(q * 16 + frow, jt * 32 + fk)];
            po = __builtin_amdgcn_mfma_f32_16x16x32_bf16(a, bv, po, 0, 0, 0);
        }
        #pragma unroll
        for (int e = 0; e < 4; ++e) {
            int r = mrow0 + g * 16 + rq + e;
            out[(size_t)r * 512 + d0 + q * 16 + frow] = po[e];
        }
        __syncthreads();
    }
}

extern "C" void kernel_launch(void* const* d_in, const int* in_sizes, int n_in,
                              void* d_out, int out_size, void* d_ws, size_t ws_size,
                              hipStream_t stream) {
    const float* x  = (const float*)d_in[0];
    const float* Wq = (const float*)d_in[1];
    const float* bq = (const float*)d_in[2];
    const float* Wk = (const float*)d_in[3];
    const float* bk = (const float*)d_in[4];
    (void)bk;
    float* out = (float*)d_out;

    u16* xh  = (u16*)d_ws;
    u16* xl  = xh + (size_t)8388608;
    u16* zh  = xl + (size_t)8388608;
    u16* zl  = zh + (size_t)8388608;
    u16* Mth = zl + (size_t)8388608;
    u16* Mtl = Mth + (size_t)262144;
    u16* xT  = Mtl + (size_t)262144;   // [4][512][4096] bf16 = 16.8 MB
    float* uv = (float*)(xT + (size_t)8388608);

    hipLaunchKernelGGL(split_xt_kernel, dim3(2048), dim3(256), 0, stream, x, xh, xl, xT);
    hipLaunchKernelGGL(mt_kernel, dim3(64), dim3(256), 0, stream, Wk, Wq, Mth, Mtl);
    hipLaunchKernelGGL(u_kernel, dim3(8), dim3(256), 0, stream, Wk, bq, uv);
    hipLaunchKernelGGL(z_kernel, dim3(512), dim3(512), 0, stream,
                       xh, xl, Mth, Mtl, uv, zh, zl);
    hipLaunchKernelGGL(attn_kernel, dim3(512), dim3(512), 0, stream,
                       zh, zl, xh, xl, xT, out);
}